// Round 3
// baseline (212.500 us; speedup 1.0000x reference)
//
#include <hip/hip_runtime.h>

// OrdinalRegressionLoss: mean over (B,4) of
//   max(x,0) - x*y + log1p(exp(-|x|)),  y[i][j] = (j < targets[i])
// B = 8388608, T = 4. Memory-bound streaming reduction:
// 134 MB logits (f32) + 33.5 MB targets (i32) read, 4 B out.
// HBM roofline for the reduce kernel: ~168 MB / 6.3 TB/s ≈ 27 µs.
// Harness-fixed per-iteration cost (d_in restore + 512 MiB ws poison) ≈ 140 µs.

typedef float  f32x4 __attribute__((ext_vector_type(4)));
typedef int    i32x4 __attribute__((ext_vector_type(4)));

#define NROWS 8388608
#define NTHR  4
#define BLOCK 256
#define GRID  2048
#define NTHREADS (BLOCK * GRID)          // 524288
#define NGROUPS  (NROWS / 4)             // 2097152 groups of 4 rows
#define GPT      (NGROUPS / NTHREADS)    // 4 groups/thread = 16 rows/thread, exact

__device__ __forceinline__ float row_loss(f32x4 x, int t) {
    // softplus(x) - x*(j<t), stable form: max(x,0) + log1p(exp(-|x|)) - x*(j<t)
    float s0 = fmaxf(x.x, 0.f) + __logf(1.f + __expf(-fabsf(x.x))) - (t > 0 ? x.x : 0.f);
    float s1 = fmaxf(x.y, 0.f) + __logf(1.f + __expf(-fabsf(x.y))) - (t > 1 ? x.y : 0.f);
    float s2 = fmaxf(x.z, 0.f) + __logf(1.f + __expf(-fabsf(x.z))) - (t > 2 ? x.z : 0.f);
    float s3 = fmaxf(x.w, 0.f) + __logf(1.f + __expf(-fabsf(x.w))) - (t > 3 ? x.w : 0.f);
    return (s0 + s1) + (s2 + s3);
}

__global__ __launch_bounds__(BLOCK) void ord_loss_reduce(
        const f32x4* __restrict__ logits4,   // NROWS rows of 4 floats
        const i32x4* __restrict__ targets4,  // NGROUPS groups of 4 targets
        float*       __restrict__ partials) { // GRID floats, write-only
    const int tid = blockIdx.x * BLOCK + threadIdx.x;

    // Each thread owns 4 groups of 4 consecutive rows (16 rows total).
    // Targets: one int4 (16 B) per group. Logits: 4x float4 per group;
    // per-instruction lane stride is 64 B but the wave's 4 instructions
    // fully consume the contiguous 4 KB span via L1 -> no HBM over-fetch.
    float acc0 = 0.f, acc1 = 0.f;
    #pragma unroll
    for (int g = 0; g < GPT; ++g) {
        const int gi = tid + g * NTHREADS;
        i32x4 t4 = __builtin_nontemporal_load(&targets4[gi]);
        f32x4 x0 = __builtin_nontemporal_load(&logits4[4 * gi + 0]);
        f32x4 x1 = __builtin_nontemporal_load(&logits4[4 * gi + 1]);
        f32x4 x2 = __builtin_nontemporal_load(&logits4[4 * gi + 2]);
        f32x4 x3 = __builtin_nontemporal_load(&logits4[4 * gi + 3]);
        acc0 += row_loss(x0, t4.x);
        acc1 += row_loss(x1, t4.y);
        acc0 += row_loss(x2, t4.z);
        acc1 += row_loss(x3, t4.w);
    }
    float acc = acc0 + acc1;

    // wave-64 butterfly reduce
    #pragma unroll
    for (int off = 32; off > 0; off >>= 1)
        acc += __shfl_down(acc, off, 64);

    __shared__ float wsum[BLOCK / 64];
    const int lane = threadIdx.x & 63;
    const int wid  = threadIdx.x >> 6;
    if (lane == 0) wsum[wid] = acc;
    __syncthreads();

    if (threadIdx.x == 0)
        partials[blockIdx.x] = (wsum[0] + wsum[1]) + (wsum[2] + wsum[3]);
}

__global__ __launch_bounds__(BLOCK) void ord_loss_final(
        const float* __restrict__ partials,
        float*       __restrict__ out) {
    // 2048 partials, 256 threads -> 8 each, coalesced
    double a = 0.0;
    #pragma unroll
    for (int k = 0; k < GRID / BLOCK; ++k)
        a += (double)partials[threadIdx.x + k * BLOCK];

    #pragma unroll
    for (int off = 32; off > 0; off >>= 1)
        a += __shfl_down(a, off, 64);

    __shared__ double wsum[BLOCK / 64];
    const int lane = threadIdx.x & 63;
    const int wid  = threadIdx.x >> 6;
    if (lane == 0) wsum[wid] = a;
    __syncthreads();

    if (threadIdx.x == 0) {
        double total = (wsum[0] + wsum[1]) + (wsum[2] + wsum[3]);
        out[0] = (float)(total / ((double)NROWS * (double)NTHR));
    }
}

extern "C" void kernel_launch(void* const* d_in, const int* in_sizes, int n_in,
                              void* d_out, int out_size, void* d_ws, size_t ws_size,
                              hipStream_t stream) {
    const f32x4* logits = (const f32x4*)d_in[0];
    const i32x4* targets = (const i32x4*)d_in[1];
    float* partials = (float*)d_ws;   // write-only: poison-safe, no memset needed
    float* out = (float*)d_out;

    ord_loss_reduce<<<GRID, BLOCK, 0, stream>>>(logits, targets, partials);
    ord_loss_final<<<1, BLOCK, 0, stream>>>(partials, out);
}